// Round 16
// baseline (896.718 us; speedup 1.0000x reference)
//
#include <hip/hip_runtime.h>
#include <hip/hip_bf16.h>
#include <stdint.h>

#define NB 32
#define NR 2048
#define NC 64
#define NO 64
#define NK 16

using bf16x8 = __attribute__((ext_vector_type(8))) short;
using f32x4  = __attribute__((ext_vector_type(4))) float;

// counted per-wave waits (rule #18: sched_barrier after the asm)
#define WAITVM(N) do { asm volatile("s_waitcnt vmcnt(" #N ")" ::: "memory"); \
                       __builtin_amdgcn_sched_barrier(0); } while (0)

__device__ __forceinline__ uint32_t f2bf(float f) {
  uint32_t u = __builtin_bit_cast(uint32_t, f);
  return (u + 0x7fffu + ((u >> 16) & 1u)) >> 16;  // RNE (bit math)
}
__device__ __forceinline__ uint32_t packbf2(float lo, float hi) {
  return f2bf(lo) | (f2bf(hi) << 16);
}
// HW pair conversion (v_cvt_pk_bf16_f32); memcpy because __hip_bfloat162 is
// not trivially copyable.
__device__ __forceinline__ uint32_t cvtpk2(float lo, float hi) {
  float2 v; v.x = lo; v.y = hi;
  __hip_bfloat162 h = __float22bfloat162_rn(v);
  uint32_t r;
  __builtin_memcpy(&r, &h, 4);
  return r;
}

__device__ __forceinline__ void gload_lds16(const float* g, float* l) {
  __builtin_amdgcn_global_load_lds(
      (const __attribute__((address_space(1))) void*)g,
      (__attribute__((address_space(3))) void*)l, 16, 0, 0);
}

// x[b][r][c] -> xbf[r][ks][mt][lane][e] bf16 (A-fragment order).
__global__ __launch_bounds__(256) void make_xbf(const float* __restrict__ x,
                                                ushort* __restrict__ xbf) {
  __shared__ float tile[32][72];
  const int r = blockIdx.x, t = threadIdx.x;
  {
    const int b = t >> 3, c0 = (t & 7) << 3;
    const float* xp = x + ((size_t)b * NR + r) * NC + c0;
    *(float4*)&tile[b][c0] = *(const float4*)xp;
    *(float4*)&tile[b][c0 + 4] = *(const float4*)(xp + 4);
  }
  __syncthreads();
  {
    const int ks = t >> 7, mt = (t >> 6) & 1, l = t & 63;
    const int b = mt * 16 + (l & 15);
    const int cb = ks * 32 + (l >> 4) * 8;
    uint4 uv;
    uv.x = packbf2(tile[b][cb + 0], tile[b][cb + 1]);
    uv.y = packbf2(tile[b][cb + 2], tile[b][cb + 3]);
    uv.z = packbf2(tile[b][cb + 4], tile[b][cb + 5]);
    uv.w = packbf2(tile[b][cb + 6], tile[b][cb + 7]);
    *(uint4*)(xbf + (size_t)r * 2048 + t * 8) = uv;
  }
}

// R13 MFMA GEMM body, templated on block->(k,r) MAP and REPS.
// MAP=0 (production / diag-B): wave w owns k = (bid&3)*4+w, rbase = (bid>>2)*8
//        -- scattered read front (16 k-siblings adjacent in bid space).
// MAP=1 (diag-A, linear front): all waves share k = bid>>6, block reads ONE
//        contiguous 512KB W slab: rbase = (bid&63)*32 + w*8. Consecutive bids
//        = consecutive slabs -> chip-wide read front marches linearly.
// REPS>1: repeat whole body (identical writes) to stretch dispatch duration
//        past the ~330us fillBuffer dispatches so rocprof top-5 shows it.
//        R15 lesson: REPS=2 ran ~230us (still crowded out) -> REPS=3.
template <int MAP, int REPS>
__global__ __launch_bounds__(256, 2) void priors_gemm_t(const ushort* __restrict__ xbf,
                                                        const float* __restrict__ W,
                                                        ushort* __restrict__ priors) {
  __shared__ float ldsW[2][4][2048];   // [buf][wave][32c x 64o] fp32, 64KB
  __shared__ ushort ldsE[4][2048];     // [wave][32b x 64o] bf16, 16KB epilogue
  const int w = threadIdx.x >> 6, lane = threadIdx.x & 63;
  const int g = lane >> 4, col = lane & 15;
  int k, rbase;
  if (MAP == 0) {
    k = (blockIdx.x & 3) * 4 + w;
    rbase = (blockIdx.x >> 2) * 8;
  } else {
    k = blockIdx.x >> 6;
    rbase = (blockIdx.x & 63) * 32 + w * 8;
  }
  const float* wbase = W + ((size_t)k * NR + rbase) * 4096;

  f32x4 acc[2][4];

  auto stage = [&](int h, int buf) {   // h = half-K-step index (ti*2+ks)
    const float* srcrow = wbase + (size_t)h * 2048;
    float* dst = &ldsW[buf][w][0] + lane * 4;
    const int j = lane & 15;
#pragma unroll
    for (int i = 0; i < 8; ++i) {
      const int c = i * 4 + (lane >> 4);
      const int gc = c >> 3;
      const int jj = j ^ (gc & 3) ^ ((gc >> 1) << 2);  // bank-spread (involution)
      gload_lds16(srcrow + c * 64 + jj * 4, dst + i * 256);
    }
  };

  auto compute = [&](bf16x8 af0, bf16x8 af1, int buf) {
    const float* pw = &ldsW[buf][w][0];
#pragma unroll
    for (int nt = 0; nt < 4; ++nt) {
      const int oo = (nt * 16 + col) ^ ((g & 3) << 2) ^ ((g >> 1) << 4);
      float f[8];
#pragma unroll
      for (int e = 0; e < 8; ++e) f[e] = pw[(g * 8 + e) * 64 + oo];
      uint4 uv;
      uv.x = cvtpk2(f[0], f[1]);
      uv.y = cvtpk2(f[2], f[3]);
      uv.z = cvtpk2(f[4], f[5]);
      uv.w = cvtpk2(f[6], f[7]);
      bf16x8 bfr = __builtin_bit_cast(bf16x8, uv);
      acc[0][nt] = __builtin_amdgcn_mfma_f32_16x16x32_bf16(af0, bfr, acc[0][nt], 0, 0, 0);
      acc[1][nt] = __builtin_amdgcn_mfma_f32_16x16x32_bf16(af1, bfr, acc[1][nt], 0, 0, 0);
    }
  };

  auto epilogue = [&](int ti) {
    // C/D layout (HW-verified m89/m91): col = lane&15, row = (lane>>4)*4 + reg.
    ushort* ep = &ldsE[w][0];
#pragma unroll
    for (int mt = 0; mt < 2; ++mt)
#pragma unroll
      for (int nt = 0; nt < 4; ++nt)
#pragma unroll
        for (int rp = 0; rp < 2; ++rp) {
          uint32_t u = cvtpk2(acc[mt][nt][rp * 2], acc[mt][nt][rp * 2 + 1]);
          const int row0 = mt * 16 + g * 4 + rp * 2;
          ep[(row0 + 0) * 64 + nt * 16 + col] = (ushort)u;
          ep[(row0 + 1) * 64 + nt * 16 + col] = (ushort)(u >> 16);
        }
    ushort* pp = priors + ((size_t)k * NR + rbase + ti) * 2048;
#pragma unroll
    for (int i = 0; i < 4; ++i) {
      uint4 v = *(const uint4*)(ep + lane * 8 + i * 512);
      *(uint4*)(pp + lane * 8 + i * 512) = v;
    }
  };

  for (int rep = 0; rep < REPS; ++rep) {
    stage(0, 0);
    for (int ti = 0; ti < 8; ++ti) {
      const size_t r = rbase + ti;
      // A-frags early so the compiler's pre-MFMA wait doesn't drain buf1 stage.
      bf16x8 a00 = *(const bf16x8*)(xbf + ((r * 2 + 0) * 2 + 0) * 512 + lane * 8);
      bf16x8 a10 = *(const bf16x8*)(xbf + ((r * 2 + 0) * 2 + 1) * 512 + lane * 8);
      bf16x8 a01 = *(const bf16x8*)(xbf + ((r * 2 + 1) * 2 + 0) * 512 + lane * 8);
      bf16x8 a11 = *(const bf16x8*)(xbf + ((r * 2 + 1) * 2 + 1) * 512 + lane * 8);
      stage(ti * 2 + 1, 1);
#pragma unroll
      for (int mt = 0; mt < 2; ++mt)
#pragma unroll
        for (int nt = 0; nt < 4; ++nt) acc[mt][nt] = f32x4{0.f, 0.f, 0.f, 0.f};
      WAITVM(12);                 // buf0's 8 loads (oldest) retired
      compute(a00, a10, 0);
      if (ti < 7) {
        stage(ti * 2 + 2, 0);     // next r's first K-step into buf0
        WAITVM(8);                // buf1's 8 retired; buf0' stays in flight
      } else {
        WAITVM(0);                // last ti: drain
      }
      compute(a01, a11, 1);
      epilogue(ti);
    }
  }
}

// Routing pass (unchanged). Block per kb (k = kb>>5, b = kb&31).
template <int PASS>
__global__ __launch_bounds__(256) void routing(const __hip_bfloat16* __restrict__ priors,
                                               float* __restrict__ Abuf,
                                               const float* __restrict__ o_prev,
                                               float* __restrict__ o_out) {
  __shared__ float o_lds[64];
  __shared__ float red_num[4][8][8];
  __shared__ float red_den[4];
  const int kb = blockIdx.x;
  const int k = kb >> 5, b = kb & 31;
  const int tid = threadIdx.x, w = tid >> 6, lane = tid & 63;
  const int g = lane >> 3, sl = lane & 7;
  const int rsub = w * 8 + g;
  const __hip_bfloat16* pbase = priors + (size_t)k * NR * NB * NO + (size_t)b * NO;
  float* ab = Abuf + (size_t)kb * NR;

  if (PASS == 1) {
    float sum[8];
#pragma unroll
    for (int j = 0; j < 8; ++j) sum[j] = 0.f;
    for (int it = 0; it < NR / 32; ++it) {
      const int r = it * 32 + rsub;
      uint4 pv = *(const uint4*)(pbase + (size_t)r * (NB * NO) + sl * 8);
      sum[0] += __builtin_bit_cast(float, pv.x << 16);
      sum[1] += __builtin_bit_cast(float, pv.x & 0xffff0000u);
      sum[2] += __builtin_bit_cast(float, pv.y << 16);
      sum[3] += __builtin_bit_cast(float, pv.y & 0xffff0000u);
      sum[4] += __builtin_bit_cast(float, pv.z << 16);
      sum[5] += __builtin_bit_cast(float, pv.z & 0xffff0000u);
      sum[6] += __builtin_bit_cast(float, pv.w << 16);
      sum[7] += __builtin_bit_cast(float, pv.w & 0xffff0000u);
    }
#pragma unroll
    for (int m = 8; m < 64; m <<= 1)
#pragma unroll
      for (int j = 0; j < 8; ++j) sum[j] += __shfl_xor(sum[j], m, 64);
    if (lane < 8) {
#pragma unroll
      for (int j = 0; j < 8; ++j) red_num[w][lane][j] = sum[j];
    }
    __syncthreads();
    if (tid < 64) {
      const int s_ = tid >> 3, j_ = tid & 7;
      float sv = (red_num[0][s_][j_] + red_num[1][s_][j_] +
                  red_num[2][s_][j_] + red_num[3][s_][j_]) * (1.f / (float)NR);
      float sq = sv * sv;
#pragma unroll
      for (int m = 1; m < 64; m <<= 1) sq += __shfl_xor(sq, m, 64);
      o_lds[tid] = (sq / (1.f + sq)) * rsqrtf(sq) * sv;  // squash
    }
    __syncthreads();
  } else {
    if (tid < 64) o_lds[tid] = o_prev[kb * 64 + tid];
    __syncthreads();
  }

  float os[8];
#pragma unroll
  for (int j = 0; j < 8; ++j) os[j] = o_lds[sl * 8 + j];

  float num[8];
#pragma unroll
  for (int j = 0; j < 8; ++j) num[j] = 0.f;
  float den = 0.f;

  for (int it = 0; it < NR / 32; ++it) {
    const int r = it * 32 + rsub;
    uint4 pv = *(const uint4*)(pbase + (size_t)r * (NB * NO) + sl * 8);
    float f[8];
    f[0] = __builtin_bit_cast(float, pv.x << 16);
    f[1] = __builtin_bit_cast(float, pv.x & 0xffff0000u);
    f[2] = __builtin_bit_cast(float, pv.y << 16);
    f[3] = __builtin_bit_cast(float, pv.y & 0xffff0000u);
    f[4] = __builtin_bit_cast(float, pv.z << 16);
    f[5] = __builtin_bit_cast(float, pv.z & 0xffff0000u);
    f[6] = __builtin_bit_cast(float, pv.w << 16);
    f[7] = __builtin_bit_cast(float, pv.w & 0xffff0000u);

    float d = 0.f;
#pragma unroll
    for (int j = 0; j < 8; ++j) d = fmaf(f[j], os[j], d);
#pragma unroll
    for (int m = 1; m < 8; m <<= 1) d += __shfl_xor(d, m, 64);

    float lg;
    if (PASS == 1) {
      lg = d;
      if (sl == 0) ab[r] = d;
    } else {
      lg = d + ab[r];
    }
    float e = __expf(lg);  // |lg| << 1, no max-subtraction needed
    den += e;
#pragma unroll
    for (int j = 0; j < 8; ++j) num[j] = fmaf(e, f[j], num[j]);
  }

#pragma unroll
  for (int m = 8; m < 64; m <<= 1) {
    den += __shfl_xor(den, m, 64);
#pragma unroll
    for (int j = 0; j < 8; ++j) num[j] += __shfl_xor(num[j], m, 64);
  }
  if (lane < 8) {
#pragma unroll
    for (int j = 0; j < 8; ++j) red_num[w][lane][j] = num[j];
    if (lane == 0) red_den[w] = den;
  }
  __syncthreads();

  if (tid < 64) {
    const int s_ = tid >> 3, j_ = tid & 7;
    float nm = red_num[0][s_][j_] + red_num[1][s_][j_] + red_num[2][s_][j_] + red_num[3][s_][j_];
    float dn = red_den[0] + red_den[1] + red_den[2] + red_den[3];
    float sv = nm / dn;
    float sq = sv * sv;
#pragma unroll
    for (int m = 1; m < 64; m <<= 1) sq += __shfl_xor(sq, m, 64);
    float ov = (sq / (1.f + sq)) * rsqrtf(sq) * sv;
    o_out[kb * 64 + tid] = ov;
  }
}

extern "C" void kernel_launch(void* const* d_in, const int* in_sizes, int n_in,
                              void* d_out, int out_size, void* d_ws, size_t ws_size,
                              hipStream_t stream) {
  const float* x = (const float*)d_in[0];          // [B][R][CIN]
  const float* W = (const float*)d_in[1];          // [K][R][CIN][COUT]
  float* out = (float*)d_out;                      // [K][B][COUT]
  char* ws = (char*)d_ws;

  size_t off = 0;
  ushort* xbf = (ushort*)(ws + off);               off += (size_t)NR * 2048 * 2;           // 8 MB
  ushort* priors = (ushort*)(ws + off);            off += (size_t)NK * NR * NB * NO * 2;   // 128 MB
  float* o1 = (float*)(ws + off);                  off += (size_t)NK * NB * NO * 4;        // 128 KB
  float* Abuf = (float*)(ws + off);                off += (size_t)NK * NB * NR * 4;        // 4 MB
  ushort* scratch = (ushort*)(ws + off);           off += (size_t)NK * NR * NB * NO * 2;   // 128 MB (diag)

  // production path (R13-exact)
  make_xbf<<<NR, 256, 0, stream>>>(x, xbf);
  priors_gemm_t<0, 1><<<(NR / 8) * (NK / 4), 256, 0, stream>>>(xbf, W, priors);
  routing<1><<<NK * NB, 256, 0, stream>>>((const __hip_bfloat16*)priors, Abuf, nullptr, o1);
  routing<2><<<NK * NB, 256, 0, stream>>>((const __hip_bfloat16*)priors, Abuf, o1, out);

  // DIAGNOSTICS (write scratch; REPS=3 so dur > 330us fills -> top-5 w/ PMC):
  // diag-A: linear read front.  diag-B: current scattered front.
  priors_gemm_t<1, 3><<<NK * (NR / 32), 256, 0, stream>>>(xbf, W, scratch);
  priors_gemm_t<0, 3><<<(NR / 8) * (NK / 4), 256, 0, stream>>>(xbf, W, scratch);
}

// Round 17
// 219.568 us; speedup vs baseline: 4.0840x; 4.0840x over previous
//
#include <hip/hip_runtime.h>
#include <hip/hip_bf16.h>
#include <stdint.h>

#define NB 32
#define NR 2048
#define NC 64
#define NO 64
#define NK 16

using bf16x8 = __attribute__((ext_vector_type(8))) short;
using f32x4  = __attribute__((ext_vector_type(4))) float;

__device__ __forceinline__ uint32_t f2bf(float f) {
  uint32_t u = __builtin_bit_cast(uint32_t, f);
  return (u + 0x7fffu + ((u >> 16) & 1u)) >> 16;  // RNE (bit math)
}
__device__ __forceinline__ uint32_t packbf2(float lo, float hi) {
  return f2bf(lo) | (f2bf(hi) << 16);
}
// HW pair conversion (v_cvt_pk_bf16_f32); memcpy because __hip_bfloat162 is
// not trivially copyable.
__device__ __forceinline__ uint32_t cvtpk2(float lo, float hi) {
  float2 v; v.x = lo; v.y = hi;
  __hip_bfloat162 h = __float22bfloat162_rn(v);
  uint32_t r;
  __builtin_memcpy(&r, &h, 4);
  return r;
}

// x -> B-operand fragments with slot map c(kgrp,e) = ks*32 + e*4 + kgrp.
// xbf[r][(ks*2+bt)*512 + lane*8 + e] = bf16(x[bt*16+(lane&15)][c(lane>>4,e)]).
// The GEMM's W A-operand uses the SAME slot->c map, so the HW k-order cancels
// (consistent-slot argument, proven by R9-R13 refchecks with a different map).
__global__ __launch_bounds__(256) void make_xbf(const float* __restrict__ x,
                                                ushort* __restrict__ xbf) {
  __shared__ float tile[32][72];
  const int r = blockIdx.x, t = threadIdx.x;
  {
    const int b = t >> 3, c0 = (t & 7) << 3;
    const float* xp = x + ((size_t)b * NR + r) * NC + c0;
    *(float4*)&tile[b][c0] = *(const float4*)xp;
    *(float4*)&tile[b][c0 + 4] = *(const float4*)(xp + 4);
  }
  __syncthreads();
  {
    const int ks = t >> 7, bt = (t >> 6) & 1, l = t & 63;
    const int kgrp = l >> 4;
    const int b = bt * 16 + (l & 15);
    const int cb = ks * 32 + kgrp;      // c = cb + e*4
    uint4 uv;
    uv.x = packbf2(tile[b][cb + 0], tile[b][cb + 4]);
    uv.y = packbf2(tile[b][cb + 8], tile[b][cb + 12]);
    uv.z = packbf2(tile[b][cb + 16], tile[b][cb + 20]);
    uv.w = packbf2(tile[b][cb + 24], tile[b][cb + 28]);
    *(uint4*)(xbf + (size_t)r * 2048 + t * 8) = uv;
  }
}

// MFMA GEMM with NO global_load_lds and NO W LDS conveyor (R16 counters:
// LDS-DMA path caps ~112us per W-pass regardless of L3 warmth; pipes idle).
// W is the A-OPERAND, loaded global->VGPR as per-lane dwords:
//   A slot (kgrp, e) of M-tile ot holds W[c(kgrp,e)][ot*16 + (lane&15)],
//   c(kgrp,e) = ks*32 + e*4 + kgrp  ->  per instr: 4 rows x 64B contiguous,
//   ot-inner reuses each 128B line twice via L1.
// x is the B-operand (xbf pre-packed, L3-hot). D: row=(lane>>4)*4+reg -> o,
// col=lane&15 -> b (m89-verified C/D layout).
// Epilogue: padded LDS bounce (72-ushort rows: dword-bank spread, kills the
// 18.9M conflict cycles measured on the old b16 writes), then R13's perfect
// 1KB-contiguous global stores. One wave per (k,r); no barriers, no asm.
__global__ __launch_bounds__(256) void priors_gemm(const ushort* __restrict__ xbf,
                                                   const float* __restrict__ W,
                                                   ushort* __restrict__ priors) {
  __shared__ ushort ldsE[4][32 * 72];  // [wave][b][o] padded, 18KB total
  const int w = threadIdx.x >> 6, lane = threadIdx.x & 63;
  const int kgrp = lane >> 4, col = lane & 15;
  const int task = blockIdx.x * 4 + w;   // 16 consecutive tasks: same r, k=0..15
  const int k = task & 15, r = task >> 4;
  const float* wbase = W + ((size_t)(k * NR + r)) * 4096;
  const ushort* xb = xbf + (size_t)r * 2048;

  // B-operand fragments (x), 8 x 16B loads, L3-resident
  bf16x8 xfrag[2][2];  // [ks][bt]
#pragma unroll
  for (int ks = 0; ks < 2; ++ks)
#pragma unroll
    for (int bt = 0; bt < 2; ++bt)
      xfrag[ks][bt] = *(const bf16x8*)(xb + (ks * 2 + bt) * 512 + lane * 8);

  f32x4 acc[4][2];  // [ot][bt]
#pragma unroll
  for (int ot = 0; ot < 4; ++ot)
#pragma unroll
    for (int bt = 0; bt < 2; ++bt) acc[ot][bt] = f32x4{0.f, 0.f, 0.f, 0.f};

#pragma unroll
  for (int ks = 0; ks < 2; ++ks) {
    float w32[4][8];  // [ot][e]
#pragma unroll
    for (int e = 0; e < 8; ++e) {
      const float* src = wbase + (ks * 32 + e * 4 + kgrp) * 64 + col;
#pragma unroll
      for (int ot = 0; ot < 4; ++ot) w32[ot][e] = src[ot * 16];
    }
#pragma unroll
    for (int ot = 0; ot < 4; ++ot) {
      uint4 uv;
      uv.x = cvtpk2(w32[ot][0], w32[ot][1]);
      uv.y = cvtpk2(w32[ot][2], w32[ot][3]);
      uv.z = cvtpk2(w32[ot][4], w32[ot][5]);
      uv.w = cvtpk2(w32[ot][6], w32[ot][7]);
      bf16x8 af = __builtin_bit_cast(bf16x8, uv);
      acc[ot][0] = __builtin_amdgcn_mfma_f32_16x16x32_bf16(af, xfrag[ks][0], acc[ot][0], 0, 0, 0);
      acc[ot][1] = __builtin_amdgcn_mfma_f32_16x16x32_bf16(af, xfrag[ks][1], acc[ot][1], 0, 0, 0);
    }
  }

  // epilogue: lane (kgrp,col) holds D rows o = ot*16+kgrp*4+reg, col b = bt*16+col
  ushort* ep = &ldsE[w][0];
#pragma unroll
  for (int ot = 0; ot < 4; ++ot)
#pragma unroll
    for (int bt = 0; bt < 2; ++bt)
#pragma unroll
      for (int pr = 0; pr < 2; ++pr) {
        uint32_t u = cvtpk2(acc[ot][bt][pr * 2], acc[ot][bt][pr * 2 + 1]);
        const int b = bt * 16 + col, o = ot * 16 + kgrp * 4 + pr * 2;
        *(uint32_t*)(&ep[b * 72 + o]) = u;  // o even, 72 even -> dword aligned
      }
  ushort* pp = priors + ((size_t)(k * NR + r)) * 2048;
#pragma unroll
  for (int i = 0; i < 4; ++i) {
    const int row = (lane >> 3) + i * 8, cc = (lane & 7) * 8;
    uint4 v = *(const uint4*)(&ep[row * 72 + cc]);   // 144B row stride: 16B-aligned
    *(uint4*)(pp + row * 64 + cc) = v;               // 1KB contiguous per instr
  }
}

// Routing pass (unchanged). Block per kb (k = kb>>5, b = kb&31).
// priors layout [k][r][b][o]. Lane: g = lane/8, sl = lane%8.
// PASS==1: phase A computes o0 = squash(mean_r p) in-block (priors read #1);
//          phase B: l = a_r = p.o0, stores a_r, writes o1 (priors read #2, L3-hot).
// PASS==2: l = a_r + p.o1; writes final output.
template <int PASS>
__global__ __launch_bounds__(256) void routing(const __hip_bfloat16* __restrict__ priors,
                                               float* __restrict__ Abuf,
                                               const float* __restrict__ o_prev,
                                               float* __restrict__ o_out) {
  __shared__ float o_lds[64];
  __shared__ float red_num[4][8][8];
  __shared__ float red_den[4];
  const int kb = blockIdx.x;
  const int k = kb >> 5, b = kb & 31;
  const int tid = threadIdx.x, w = tid >> 6, lane = tid & 63;
  const int g = lane >> 3, sl = lane & 7;
  const int rsub = w * 8 + g;
  const __hip_bfloat16* pbase = priors + (size_t)k * NR * NB * NO + (size_t)b * NO;
  float* ab = Abuf + (size_t)kb * NR;

  if (PASS == 1) {
    float sum[8];
#pragma unroll
    for (int j = 0; j < 8; ++j) sum[j] = 0.f;
    for (int it = 0; it < NR / 32; ++it) {
      const int r = it * 32 + rsub;
      uint4 pv = *(const uint4*)(pbase + (size_t)r * (NB * NO) + sl * 8);
      sum[0] += __builtin_bit_cast(float, pv.x << 16);
      sum[1] += __builtin_bit_cast(float, pv.x & 0xffff0000u);
      sum[2] += __builtin_bit_cast(float, pv.y << 16);
      sum[3] += __builtin_bit_cast(float, pv.y & 0xffff0000u);
      sum[4] += __builtin_bit_cast(float, pv.z << 16);
      sum[5] += __builtin_bit_cast(float, pv.z & 0xffff0000u);
      sum[6] += __builtin_bit_cast(float, pv.w << 16);
      sum[7] += __builtin_bit_cast(float, pv.w & 0xffff0000u);
    }
#pragma unroll
    for (int m = 8; m < 64; m <<= 1)
#pragma unroll
      for (int j = 0; j < 8; ++j) sum[j] += __shfl_xor(sum[j], m, 64);
    if (lane < 8) {
#pragma unroll
      for (int j = 0; j < 8; ++j) red_num[w][lane][j] = sum[j];
    }
    __syncthreads();
    if (tid < 64) {
      const int s_ = tid >> 3, j_ = tid & 7;
      float sv = (red_num[0][s_][j_] + red_num[1][s_][j_] +
                  red_num[2][s_][j_] + red_num[3][s_][j_]) * (1.f / (float)NR);
      float sq = sv * sv;
#pragma unroll
      for (int m = 1; m < 64; m <<= 1) sq += __shfl_xor(sq, m, 64);
      o_lds[tid] = (sq / (1.f + sq)) * rsqrtf(sq) * sv;  // squash
    }
    __syncthreads();
  } else {
    if (tid < 64) o_lds[tid] = o_prev[kb * 64 + tid];
    __syncthreads();
  }

  float os[8];
#pragma unroll
  for (int j = 0; j < 8; ++j) os[j] = o_lds[sl * 8 + j];

  float num[8];
#pragma unroll
  for (int j = 0; j < 8; ++j) num[j] = 0.f;
  float den = 0.f;

  for (int it = 0; it < NR / 32; ++it) {
    const int r = it * 32 + rsub;
    uint4 pv = *(const uint4*)(pbase + (size_t)r * (NB * NO) + sl * 8);
    float f[8];
    f[0] = __builtin_bit_cast(float, pv.x << 16);
    f[1] = __builtin_bit_cast(float, pv.x & 0xffff0000u);
    f[2] = __builtin_bit_cast(float, pv.y << 16);
    f[3] = __builtin_bit_cast(float, pv.y & 0xffff0000u);
    f[4] = __builtin_bit_cast(float, pv.z << 16);
    f[5] = __builtin_bit_cast(float, pv.z & 0xffff0000u);
    f[6] = __builtin_bit_cast(float, pv.w << 16);
    f[7] = __builtin_bit_cast(float, pv.w & 0xffff0000u);

    float d = 0.f;
#pragma unroll
    for (int j = 0; j < 8; ++j) d = fmaf(f[j], os[j], d);
#pragma unroll
    for (int m = 1; m < 8; m <<= 1) d += __shfl_xor(d, m, 64);

    float lg;
    if (PASS == 1) {
      lg = d;
      if (sl == 0) ab[r] = d;
    } else {
      lg = d + ab[r];
    }
    float e = __expf(lg);  // |lg| << 1, no max-subtraction needed
    den += e;
#pragma unroll
    for (int j = 0; j < 8; ++j) num[j] = fmaf(e, f[j], num[j]);
  }

#pragma unroll
  for (int m = 8; m < 64; m <<= 1) {
    den += __shfl_xor(den, m, 64);
#pragma unroll
    for (int j = 0; j < 8; ++j) num[j] += __shfl_xor(num[j], m, 64);
  }
  if (lane < 8) {
#pragma unroll
    for (int j = 0; j < 8; ++j) red_num[w][lane][j] = num[j];
    if (lane == 0) red_den[w] = den;
  }
  __syncthreads();

  if (tid < 64) {
    const int s_ = tid >> 3, j_ = tid & 7;
    float nm = red_num[0][s_][j_] + red_num[1][s_][j_] + red_num[2][s_][j_] + red_num[3][s_][j_];
    float dn = red_den[0] + red_den[1] + red_den[2] + red_den[3];
    float sv = nm / dn;
    float sq = sv * sv;
#pragma unroll
    for (int m = 1; m < 64; m <<= 1) sq += __shfl_xor(sq, m, 64);
    float ov = (sq / (1.f + sq)) * rsqrtf(sq) * sv;
    o_out[kb * 64 + tid] = ov;
  }
}

extern "C" void kernel_launch(void* const* d_in, const int* in_sizes, int n_in,
                              void* d_out, int out_size, void* d_ws, size_t ws_size,
                              hipStream_t stream) {
  const float* x = (const float*)d_in[0];          // [B][R][CIN]
  const float* W = (const float*)d_in[1];          // [K][R][CIN][COUT]
  float* out = (float*)d_out;                      // [K][B][COUT]
  char* ws = (char*)d_ws;

  size_t off = 0;
  ushort* xbf = (ushort*)(ws + off);               off += (size_t)NR * 2048 * 2;           // 8 MB
  ushort* priors = (ushort*)(ws + off);            off += (size_t)NK * NR * NB * NO * 2;   // 128 MB
  float* o1 = (float*)(ws + off);                  off += (size_t)NK * NB * NO * 4;        // 128 KB
  float* Abuf = (float*)(ws + off);                off += (size_t)NK * NB * NR * 4;        // 4 MB

  make_xbf<<<NR, 256, 0, stream>>>(x, xbf);
  priors_gemm<<<(NR * NK) / 4, 256, 0, stream>>>(xbf, W, priors);
  routing<1><<<NK * NB, 256, 0, stream>>>((const __hip_bfloat16*)priors, Abuf, nullptr, o1);
  routing<2><<<NK * NB, 256, 0, stream>>>((const __hip_bfloat16*)priors, Abuf, o1, out);
}